// Round 1
// baseline (1752.943 us; speedup 1.0000x reference)
//
#include <hip/hip_runtime.h>
#include <hip/hip_bf16.h>
#include <math.h>

#define NB 4
#define SQ 1024
#define DM 1024
#define NH 16
#define HDm 64
#define NE 8
#define FFd 4096
#define NTOK 4096
#define RTOT 9216
#define EPSF 1e-6f

typedef __attribute__((ext_vector_type(8))) short bf16x8_t;
typedef __attribute__((ext_vector_type(4))) float f32x4_t;
typedef const __attribute__((address_space(1))) void* gas_t;
typedef __attribute__((address_space(3))) void* las_t;

__device__ __forceinline__ float b2f(unsigned short u){
  return __uint_as_float(((unsigned int)u) << 16);
}
__device__ __forceinline__ unsigned short f2b(float f){
  __hip_bfloat16 h = __float2bfloat16(f);
  unsigned short u;
  __builtin_memcpy(&u, &h, 2);
  return u;
}

// ---------------- fp32 -> bf16 convert ----------------
__global__ __launch_bounds__(256) void convert_k(const float* __restrict__ s,
                                                 unsigned short* __restrict__ d, int n4){
  int i = blockIdx.x*256 + threadIdx.x;
  if (i >= n4) return;
  float4 v = ((const float4*)s)[i];
  ushort4 o; o.x=f2b(v.x); o.y=f2b(v.y); o.z=f2b(v.z); o.w=f2b(v.w);
  ((ushort4*)d)[i] = o;
}

// ---------------- RMSNorm (fp32), one block per row ----------------
__global__ __launch_bounds__(256) void rmsnorm_k(const float* __restrict__ x,
                                                 const float* __restrict__ w,
                                                 float* __restrict__ o){
  int row = blockIdx.x; int t = threadIdx.x;
  float4 v = ((const float4*)(x + (size_t)row*DM))[t];
  float ss = v.x*v.x + v.y*v.y + v.z*v.z + v.w*v.w;
  #pragma unroll
  for (int d=32; d; d>>=1) ss += __shfl_down(ss, d, 64);
  __shared__ float red[4];
  int wid = t>>6, ln = t&63;
  if (ln==0) red[wid] = ss;
  __syncthreads();
  float tot = red[0]+red[1]+red[2]+red[3];
  float sc = 1.0f/sqrtf(tot*(1.0f/DM) + EPSF);
  float4 wv = ((const float4*)w)[t];
  float4 ov = { v.x*sc*wv.x, v.y*sc*wv.y, v.z*sc*wv.z, v.w*sc*wv.w };
  ((float4*)(o + (size_t)row*DM))[t] = ov;
}

// ---------------- fp32 NT GEMM: C = A @ Bw^T (+resid). 64x64 tile ----------------
__global__ __launch_bounds__(256) void gemm_nt_f32(
  const float* __restrict__ A,
  const float* __restrict__ B0, const float* __restrict__ B1, const float* __restrict__ B2,
  float* __restrict__ C0, float* __restrict__ C1, float* __restrict__ C2,
  const float* __restrict__ resid, int Kd, int Ncols)
{
  const float* Bw = (blockIdx.z==0)?B0:(blockIdx.z==1)?B1:B2;
  float* C = (blockIdx.z==0)?C0:(blockIdx.z==1)?C1:C2;
  __shared__ float At[16][68];
  __shared__ float Bt[16][68];
  const int t = threadIdx.x;
  const int row0 = blockIdx.y*64, col0 = blockIdx.x*64;
  const int lr = t>>2, lk = (t&3)*4;
  const int ty = t>>4, tx = t&15;
  float acc[4][4] = {};
  const float* pA = A  + (size_t)(row0+lr)*Kd + lk;
  const float* pB = Bw + (size_t)(col0+lr)*Kd + lk;
  for (int k0=0; k0<Kd; k0+=16){
    float4 a = *(const float4*)(pA + k0);
    float4 b = *(const float4*)(pB + k0);
    __syncthreads();
    At[lk+0][lr]=a.x; At[lk+1][lr]=a.y; At[lk+2][lr]=a.z; At[lk+3][lr]=a.w;
    Bt[lk+0][lr]=b.x; Bt[lk+1][lr]=b.y; Bt[lk+2][lr]=b.z; Bt[lk+3][lr]=b.w;
    __syncthreads();
    #pragma unroll
    for (int kk=0;kk<16;kk++){
      float4 av = *(const float4*)&At[kk][ty*4];
      float4 bv = *(const float4*)&Bt[kk][tx*4];
      float a4[4]={av.x,av.y,av.z,av.w};
      float b4[4]={bv.x,bv.y,bv.z,bv.w};
      #pragma unroll
      for (int i=0;i<4;i++)
        #pragma unroll
        for (int j=0;j<4;j++)
          acc[i][j] = fmaf(a4[i], b4[j], acc[i][j]);
    }
  }
  #pragma unroll
  for (int i=0;i<4;i++){
    int r = row0 + ty*4 + i;
    float4 v = { acc[i][0], acc[i][1], acc[i][2], acc[i][3] };
    if (resid){
      float4 rv = *(const float4*)(resid + (size_t)r*Ncols + col0 + tx*4);
      v.x+=rv.x; v.y+=rv.y; v.z+=rv.z; v.w+=rv.w;
    }
    *(float4*)(C + (size_t)r*Ncols + col0 + tx*4) = v;
  }
}

// ---------------- RoPE in-place on qh, kh ----------------
__global__ __launch_bounds__(256) void rope_k(float* __restrict__ qh, float* __restrict__ kh,
  const float* __restrict__ fc, const float* __restrict__ fs){
  int idx = blockIdx.x*256 + threadIdx.x;
  if (idx >= NTOK*NH*32) return;
  int i = idx & 31;
  int h = (idx>>5) & (NH-1);
  int n = idx >> 9;
  int s = n & (SQ-1);
  float c = fc[s*32+i], sn = fs[s*32+i];
  size_t base = (size_t)n*DM + h*HDm + 2*i;
  float xr = qh[base], xi = qh[base+1];
  qh[base]   = xr*c - xi*sn;
  qh[base+1] = xr*sn + xi*c;
  xr = kh[base]; xi = kh[base+1];
  kh[base]   = xr*c - xi*sn;
  kh[base+1] = xr*sn + xi*c;
}

// ---------------- fp32 flash attention, 64x64 tiles ----------------
__global__ __launch_bounds__(256) void flash_k(
  const float* __restrict__ qh, const float* __restrict__ kh, const float* __restrict__ vh,
  float* __restrict__ ctx, const int* __restrict__ causp)
{
  __shared__ float Qt[64][68];   // [hd][qrow]
  __shared__ float KP[64][68];   // Kt [hd][krow] then reused as Pt [krow][qrow]
  __shared__ float Vs[64][68];   // [krow][hd]
  __shared__ float red[64][17];
  __shared__ float mrow[64], lrow[64], arow[64];
  const int qt = blockIdx.x;
  const int b = blockIdx.y >> 4, h = blockIdx.y & 15;
  const int t = threadIdx.x;
  const int row = t>>2, cb = (t&3)*16;
  const int ty = t>>4, tx = t&15;
  const size_t headoff = ((size_t)b*SQ)*DM + (size_t)h*HDm;
  const int q0 = qt*64;
  {
    const float* qp = qh + headoff + (size_t)(q0+row)*DM + cb;
    #pragma unroll
    for (int j=0;j<4;j++){
      float4 v = *(const float4*)(qp + 4*j);
      Qt[cb+4*j+0][row]=v.x; Qt[cb+4*j+1][row]=v.y; Qt[cb+4*j+2][row]=v.z; Qt[cb+4*j+3][row]=v.w;
    }
  }
  if (t<64){ mrow[t]=-1e30f; lrow[t]=0.f; }
  float O[4][4] = {};
  const int causal = *causp;
  const int ktmax = causal ? qt : (SQ/64 - 1);
  for (int kt=0; kt<=ktmax; ++kt){
    const int k0 = kt*64;
    __syncthreads();
    {
      const float* kp_ = kh + headoff + (size_t)(k0+row)*DM + cb;
      const float* vp_ = vh + headoff + (size_t)(k0+row)*DM + cb;
      #pragma unroll
      for (int j=0;j<4;j++){
        float4 v = *(const float4*)(kp_ + 4*j);
        KP[cb+4*j+0][row]=v.x; KP[cb+4*j+1][row]=v.y; KP[cb+4*j+2][row]=v.z; KP[cb+4*j+3][row]=v.w;
        float4 u = *(const float4*)(vp_ + 4*j);
        *(float4*)&Vs[row][cb+4*j] = u;
      }
    }
    __syncthreads();
    float Sv[4][4] = {};
    #pragma unroll 16
    for (int kk=0;kk<64;kk++){
      float4 qa = *(const float4*)&Qt[kk][ty*4];
      float4 kb = *(const float4*)&KP[kk][tx*4];
      float a4[4]={qa.x,qa.y,qa.z,qa.w}, b4[4]={kb.x,kb.y,kb.z,kb.w};
      #pragma unroll
      for (int i=0;i<4;i++)
        #pragma unroll
        for (int j=0;j<4;j++)
          Sv[i][j] = fmaf(a4[i], b4[j], Sv[i][j]);
    }
    #pragma unroll
    for (int i=0;i<4;i++){
      float lm = -3.0e30f;
      #pragma unroll
      for (int j=0;j<4;j++){
        float s = Sv[i][j]*0.125f;
        if (causal && (k0+tx*4+j) > (q0+ty*4+i)) s = -1e30f;
        Sv[i][j] = s;
        lm = fmaxf(lm, s);
      }
      red[ty*4+i][tx] = lm;
    }
    __syncthreads();
    if (t<64){
      float m = red[t][0];
      #pragma unroll
      for (int j=1;j<16;j++) m = fmaxf(m, red[t][j]);
      float mo = mrow[t];
      float mn = fmaxf(mo, m);
      float al = expf(mo - mn);
      mrow[t]=mn; arow[t]=al; lrow[t]*=al;
    }
    __syncthreads();
    #pragma unroll
    for (int i=0;i<4;i++){
      int r = ty*4+i;
      float mn = mrow[r];
      float rs = 0.f;
      #pragma unroll
      for (int j=0;j<4;j++){
        float p = expf(Sv[i][j]-mn);
        KP[tx*4+j][r] = p;   // Pt[key][qrow], aliases Kt (done reading)
        rs += p;
      }
      red[r][tx] = rs;
    }
    __syncthreads();
    if (t<64){
      float s_=0.f;
      #pragma unroll
      for (int j=0;j<16;j++) s_ += red[t][j];
      lrow[t] += s_;
    }
    #pragma unroll
    for (int i=0;i<4;i++){
      float al = arow[ty*4+i];
      #pragma unroll
      for (int j=0;j<4;j++) O[i][j]*=al;
    }
    #pragma unroll 16
    for (int kk=0;kk<64;kk++){
      float4 pa = *(const float4*)&KP[kk][ty*4];
      float4 vb = *(const float4*)&Vs[kk][tx*4];
      float a4[4]={pa.x,pa.y,pa.z,pa.w}, b4[4]={vb.x,vb.y,vb.z,vb.w};
      #pragma unroll
      for (int i=0;i<4;i++)
        #pragma unroll
        for (int j=0;j<4;j++)
          O[i][j] = fmaf(a4[i], b4[j], O[i][j]);
    }
  }
  __syncthreads();
  #pragma unroll
  for (int i=0;i<4;i++){
    float il = 1.0f/lrow[ty*4+i];
    float4 ov = { O[i][0]*il, O[i][1]*il, O[i][2]*il, O[i][3]*il };
    *(float4*)(ctx + headoff + (size_t)(q0+ty*4+i)*DM + tx*4) = ov;
  }
}

// ---------------- router: fp32 logits, top-2, counts ----------------
__global__ __launch_bounds__(256) void router_k(
  const float* __restrict__ hn, const float* __restrict__ rw, const float* __restrict__ rb,
  int* __restrict__ topi, float* __restrict__ topp, int* __restrict__ counts)
{
  const int n = blockIdx.x, t = threadIdx.x;
  float4 x = ((const float4*)(hn + (size_t)n*DM))[t];
  float p[NE];
  #pragma unroll
  for (int e=0;e<NE;e++){
    float4 wv = ((const float4*)(rw + (size_t)e*DM))[t];
    p[e] = x.x*wv.x + x.y*wv.y + x.z*wv.z + x.w*wv.w;
  }
  #pragma unroll
  for (int e=0;e<NE;e++)
    #pragma unroll
    for (int d=32; d; d>>=1) p[e] += __shfl_down(p[e], d, 64);
  __shared__ float red[4][NE];
  int wid=t>>6, ln=t&63;
  if (ln==0){
    #pragma unroll
    for (int e=0;e<NE;e++) red[wid][e]=p[e];
  }
  __syncthreads();
  if (t==0){
    float v1=-3e30f, v2=-3e30f; int i1=0, i2=0;
    for (int e=0;e<NE;e++){
      float v = red[0][e]+red[1][e]+red[2][e]+red[3][e]+rb[e];
      if (v > v1){ v2=v1;i2=i1; v1=v;i1=e; }
      else if (v > v2){ v2=v;i2=e; }
    }
    float ex = expf(v2-v1);
    float g1 = 1.0f/(1.0f+ex);
    float g2 = ex*g1;
    topi[2*n]=i1; topi[2*n+1]=i2;
    topp[2*n]=g1; topp[2*n+1]=g2;
    atomicAdd(&counts[i1],1); atomicAdd(&counts[i2],1);
  }
}

__global__ void offsets_k(const int* __restrict__ counts, int* __restrict__ offs){
  if (blockIdx.x==0 && threadIdx.x==0){
    int run=0;
    for (int e=0;e<NE;e++){ offs[e]=run; run += (counts[e]+127)&~127; }
    offs[NE]=run;
  }
}

__global__ __launch_bounds__(256) void assign_k(const int* __restrict__ topi,
  const int* __restrict__ offs, int* __restrict__ cursor,
  int* __restrict__ list, int* __restrict__ inv){
  int t = blockIdx.x*256 + threadIdx.x;
  if (t >= NTOK*2) return;
  int e = topi[t];
  int slot = atomicAdd(&cursor[e], 1);
  int pos = offs[e] + slot;
  list[pos] = t>>1;
  inv[t] = pos;
}

__global__ __launch_bounds__(256) void gather_k(const float* __restrict__ hn,
  const int* __restrict__ offs, const int* __restrict__ counts, const int* __restrict__ list,
  unsigned short* __restrict__ xg){
  const int p = blockIdx.x;
  if (p >= offs[NE]) return;
  int e=0;
  while (offs[e+1] <= p) ++e;
  const int t = threadIdx.x;
  ushort4 o;
  if (p - offs[e] < counts[e]){
    int n = list[p];
    float4 x = ((const float4*)(hn + (size_t)n*DM))[t];
    o.x=f2b(x.x); o.y=f2b(x.y); o.z=f2b(x.z); o.w=f2b(x.w);
  } else { o.x=0; o.y=0; o.z=0; o.w=0; }
  ((ushort4*)(xg + (size_t)p*DM))[t] = o;
}

// ---------------- bf16 MFMA NT GEMM over expert-compacted rows ----------------
__global__ __launch_bounds__(256) void gemm_moe_bf16(
  const unsigned short* __restrict__ Aall, const unsigned short* __restrict__ Wall,
  unsigned short* __restrict__ Call, const int* __restrict__ offs, int Kd, int Ncols)
{
  const int row0 = blockIdx.y*128;
  if (row0 >= offs[NE]) return;
  int e=0;
  while (offs[e+1] <= row0) ++e;
  const unsigned short* Wp = Wall + (size_t)e*Ncols*Kd;
  const int col0 = blockIdx.x*128;
  __shared__ unsigned short As[128*32];
  __shared__ unsigned short Bs[128*32];
  const int t = threadIdx.x;
  const int w = t>>6, lane = t&63;
  const int wm = w>>1, wn = w&1;
  const int lm = lane&15, fk = (lane>>4)*8;
  f32x4_t acc[4][4];
  #pragma unroll
  for (int i=0;i<4;i++)
    #pragma unroll
    for (int j=0;j<4;j++){ f32x4_t z = {0.f,0.f,0.f,0.f}; acc[i][j]=z; }
  for (int k0=0;k0<Kd;k0+=32){
    __syncthreads();
    #pragma unroll
    for (int j=0;j<2;j++){
      const int chunk = j*4 + w;
      const int gt = chunk*64 + lane;
      const int rw_ = gt>>2, kp = (gt&3)*8;
      __builtin_amdgcn_global_load_lds((gas_t)(Aall + (size_t)(row0+rw_)*Kd + k0 + kp),
                                       (las_t)(As + chunk*512), 16, 0, 0);
      __builtin_amdgcn_global_load_lds((gas_t)(Wp + (size_t)(col0+rw_)*Kd + k0 + kp),
                                       (las_t)(Bs + chunk*512), 16, 0, 0);
    }
    __syncthreads();
    bf16x8_t af[4], bfr[4];
    #pragma unroll
    for (int f=0;f<4;f++){
      af[f]  = *(const bf16x8_t*)(As + (size_t)(wm*64 + f*16 + lm)*32 + fk);
      bfr[f] = *(const bf16x8_t*)(Bs + (size_t)(wn*64 + f*16 + lm)*32 + fk);
    }
    #pragma unroll
    for (int i=0;i<4;i++)
      #pragma unroll
      for (int j=0;j<4;j++)
        acc[i][j] = __builtin_amdgcn_mfma_f32_16x16x32_bf16(af[i], bfr[j], acc[i][j], 0, 0, 0);
  }
  const int rbase = row0 + wm*64 + (lane>>4)*4;
  const int cbase = col0 + wn*64 + lm;
  #pragma unroll
  for (int i=0;i<4;i++)
    #pragma unroll
    for (int j=0;j<4;j++)
      #pragma unroll
      for (int r=0;r<4;r++)
        Call[(size_t)(rbase + i*16 + r)*Ncols + cbase + j*16] = f2b(acc[i][j][r]);
}

__global__ __launch_bounds__(256) void silu_mul_k(unsigned short* __restrict__ h1,
                                                  const unsigned short* __restrict__ h3){
  size_t i = (size_t)blockIdx.x*256 + threadIdx.x;
  ushort4 a = ((const ushort4*)h1)[i];
  ushort4 b = ((const ushort4*)h3)[i];
  ushort4 o;
  float fa, fb, s_;
  fa=b2f(a.x); fb=b2f(b.x); s_=fa/(1.f+__expf(-fa)); o.x=f2b(s_*fb);
  fa=b2f(a.y); fb=b2f(b.y); s_=fa/(1.f+__expf(-fa)); o.y=f2b(s_*fb);
  fa=b2f(a.z); fb=b2f(b.z); s_=fa/(1.f+__expf(-fa)); o.z=f2b(s_*fb);
  fa=b2f(a.w); fb=b2f(b.w); s_=fa/(1.f+__expf(-fa)); o.w=f2b(s_*fb);
  ((ushort4*)h1)[i] = o;
}

__global__ __launch_bounds__(256) void combine_k(const float* __restrict__ h,
  const unsigned short* __restrict__ yb, const float* __restrict__ topp,
  const int* __restrict__ inv, float* __restrict__ out)
{
  const int n = blockIdx.x, t = threadIdx.x;
  const int p0 = inv[2*n], p1 = inv[2*n+1];
  const float g0 = topp[2*n], g1 = topp[2*n+1];
  float4 hv = ((const float4*)(h + (size_t)n*DM))[t];
  ushort4 y0 = ((const ushort4*)(yb + (size_t)p0*DM))[t];
  ushort4 y1 = ((const ushort4*)(yb + (size_t)p1*DM))[t];
  float4 ov;
  ov.x = hv.x + g0*b2f(y0.x) + g1*b2f(y1.x);
  ov.y = hv.y + g0*b2f(y0.y) + g1*b2f(y1.y);
  ov.z = hv.z + g0*b2f(y0.z) + g1*b2f(y1.z);
  ov.w = hv.w + g0*b2f(y0.w) + g1*b2f(y1.w);
  ((float4*)(out + (size_t)n*DM))[t] = ov;
}

extern "C" void kernel_launch(void* const* d_in, const int* in_sizes, int n_in,
                              void* d_out, int out_size, void* d_ws, size_t ws_size,
                              hipStream_t stream)
{
  (void)in_sizes; (void)n_in; (void)out_size; (void)ws_size;
  const float* q    = (const float*)d_in[0];
  const float* fc   = (const float*)d_in[3];
  const float* fs   = (const float*)d_in[4];
  const float* attw = (const float*)d_in[5];
  const float* ffnw = (const float*)d_in[6];
  const float* wq   = (const float*)d_in[7];
  const float* wk   = (const float*)d_in[8];
  const float* wv   = (const float*)d_in[9];
  const float* wo   = (const float*)d_in[10];
  const float* rw   = (const float*)d_in[11];
  const float* rb   = (const float*)d_in[12];
  const float* w1   = (const float*)d_in[13];
  const float* w2   = (const float*)d_in[14];
  const float* w3   = (const float*)d_in[15];
  const int*   caus = (const int*)d_in[16];
  float* out = (float*)d_out;

  char* ws = (char*)d_ws;
  size_t off = 0;
  auto take = [&](size_t bytes)->char*{ char* r = ws + off; off += (bytes + 255) & ~(size_t)255; return r; };
  float* qn   = (float*)take((size_t)NTOK*DM*4);
  float* qh   = (float*)take((size_t)NTOK*DM*4);
  float* kh   = (float*)take((size_t)NTOK*DM*4);
  float* vh   = (float*)take((size_t)NTOK*DM*4);
  float* hbuf = (float*)take((size_t)NTOK*DM*4);
  unsigned short* h1  = (unsigned short*)take((size_t)RTOT*FFd*2);
  unsigned short* h3  = (unsigned short*)take((size_t)RTOT*FFd*2);
  unsigned short* yb  = (unsigned short*)take((size_t)RTOT*DM*2);
  unsigned short* w1b = (unsigned short*)take((size_t)NE*FFd*DM*2);
  unsigned short* w3b = (unsigned short*)take((size_t)NE*FFd*DM*2);
  unsigned short* w2b = (unsigned short*)take((size_t)NE*FFd*DM*2);
  int*   counts = (int*)take(64);
  int*   cursor = counts + 8;
  int*   offs   = (int*)take(64);
  int*   topi   = (int*)take((size_t)NTOK*2*4);
  float* topp   = (float*)take((size_t)NTOK*2*4);
  int*   list   = (int*)take((size_t)RTOT*4);
  int*   inv    = (int*)take((size_t)NTOK*2*4);
  // aliases (lifetimes disjoint):
  float* ctx = qn;                      // flash output overwrites qn
  float* hn  = qh;                      // rmsnorm2 output overwrites qh
  unsigned short* xg = (unsigned short*)kh;  // gathered bf16 tokens overwrite kh(+vh)

  const int nw4 = NE*FFd*DM/4;  // 8388608
  convert_k<<<nw4/256, 256, 0, stream>>>(w1, w1b, nw4);
  convert_k<<<nw4/256, 256, 0, stream>>>(w3, w3b, nw4);
  convert_k<<<nw4/256, 256, 0, stream>>>(w2, w2b, nw4);

  rmsnorm_k<<<NTOK, 256, 0, stream>>>(q, attw, qn);
  gemm_nt_f32<<<dim3(16,64,3), 256, 0, stream>>>(qn, wq, wk, wv, qh, kh, vh, nullptr, DM, DM);
  rope_k<<<NTOK*NH*32/256, 256, 0, stream>>>(qh, kh, fc, fs);
  flash_k<<<dim3(SQ/64, NB*NH), 256, 0, stream>>>(qh, kh, vh, ctx, caus);
  gemm_nt_f32<<<dim3(16,64,1), 256, 0, stream>>>(ctx, wo, wo, wo, hbuf, hbuf, hbuf, q, DM, DM);
  rmsnorm_k<<<NTOK, 256, 0, stream>>>(hbuf, ffnw, hn);

  hipMemsetAsync(counts, 0, 64, stream);
  router_k<<<NTOK, 256, 0, stream>>>(hn, rw, rb, topi, topp, counts);
  offsets_k<<<1, 64, 0, stream>>>(counts, offs);
  assign_k<<<NTOK*2/256, 256, 0, stream>>>(topi, offs, cursor, list, inv);
  gather_k<<<RTOT, 256, 0, stream>>>(hn, offs, counts, list, xg);

  gemm_moe_bf16<<<dim3(FFd/128, RTOT/128), 256, 0, stream>>>(xg, w1b, h1, offs, DM, FFd);
  gemm_moe_bf16<<<dim3(FFd/128, RTOT/128), 256, 0, stream>>>(xg, w3b, h3, offs, DM, FFd);
  silu_mul_k<<<RTOT*FFd/4/256, 256, 0, stream>>>(h1, h3);
  gemm_moe_bf16<<<dim3(DM/128, RTOT/128), 256, 0, stream>>>(h1, w2b, yb, offs, FFd, DM);
  combine_k<<<NTOK, 256, 0, stream>>>(hbuf, yb, topp, inv, out);
}

// Round 2
// 1417.474 us; speedup vs baseline: 1.2367x; 1.2367x over previous
//
#include <hip/hip_runtime.h>
#include <hip/hip_bf16.h>
#include <math.h>

#define NB 4
#define SQ 1024
#define DM 1024
#define NH 16
#define HDm 64
#define NE 8
#define FFd 4096
#define NTOK 4096
#define RTOT 9216
#define EPSF 1e-6f

typedef __attribute__((ext_vector_type(8))) short bf16x8_t;
typedef __attribute__((ext_vector_type(4))) float f32x4_t;
typedef const __attribute__((address_space(1))) void* gas_t;
typedef __attribute__((address_space(3))) void* las_t;

__device__ __forceinline__ float b2f(unsigned short u){
  return __uint_as_float(((unsigned int)u) << 16);
}
__device__ __forceinline__ unsigned short f2b(float f){
  __hip_bfloat16 h = __float2bfloat16(f);
  unsigned short u;
  __builtin_memcpy(&u, &h, 2);
  return u;
}

// ---------------- fp32 -> bf16 convert ----------------
__global__ __launch_bounds__(256) void convert_k(const float* __restrict__ s,
                                                 unsigned short* __restrict__ d, int n4){
  int i = blockIdx.x*256 + threadIdx.x;
  if (i >= n4) return;
  float4 v = ((const float4*)s)[i];
  ushort4 o; o.x=f2b(v.x); o.y=f2b(v.y); o.z=f2b(v.z); o.w=f2b(v.w);
  ((ushort4*)d)[i] = o;
}

// ---------------- fp32 -> bf16 hi/lo split ----------------
__global__ __launch_bounds__(256) void split_k(const float* __restrict__ s,
                                               unsigned short* __restrict__ hi,
                                               unsigned short* __restrict__ lo, int n4){
  int i = blockIdx.x*256 + threadIdx.x;
  if (i >= n4) return;
  float4 v = ((const float4*)s)[i];
  ushort4 h, l;
  h.x=f2b(v.x); l.x=f2b(v.x - b2f(h.x));
  h.y=f2b(v.y); l.y=f2b(v.y - b2f(h.y));
  h.z=f2b(v.z); l.z=f2b(v.z - b2f(h.z));
  h.w=f2b(v.w); l.w=f2b(v.w - b2f(h.w));
  ((ushort4*)hi)[i] = h;
  ((ushort4*)lo)[i] = l;
}

// ---------------- RMSNorm (fp32 out), one block per row ----------------
__global__ __launch_bounds__(256) void rmsnorm_k(const float* __restrict__ x,
                                                 const float* __restrict__ w,
                                                 float* __restrict__ o){
  int row = blockIdx.x; int t = threadIdx.x;
  float4 v = ((const float4*)(x + (size_t)row*DM))[t];
  float ss = v.x*v.x + v.y*v.y + v.z*v.z + v.w*v.w;
  #pragma unroll
  for (int d=32; d; d>>=1) ss += __shfl_down(ss, d, 64);
  __shared__ float red[4];
  int wid = t>>6, ln = t&63;
  if (ln==0) red[wid] = ss;
  __syncthreads();
  float tot = red[0]+red[1]+red[2]+red[3];
  float sc = 1.0f/sqrtf(tot*(1.0f/DM) + EPSF);
  float4 wv = ((const float4*)w)[t];
  float4 ov = { v.x*sc*wv.x, v.y*sc*wv.y, v.z*sc*wv.z, v.w*sc*wv.w };
  ((float4*)(o + (size_t)row*DM))[t] = ov;
}

// ---------------- RMSNorm with split bf16 output ----------------
__global__ __launch_bounds__(256) void rmsnorm_split_k(const float* __restrict__ x,
                                                       const float* __restrict__ w,
                                                       unsigned short* __restrict__ hi,
                                                       unsigned short* __restrict__ lo){
  int row = blockIdx.x; int t = threadIdx.x;
  float4 v = ((const float4*)(x + (size_t)row*DM))[t];
  float ss = v.x*v.x + v.y*v.y + v.z*v.z + v.w*v.w;
  #pragma unroll
  for (int d=32; d; d>>=1) ss += __shfl_down(ss, d, 64);
  __shared__ float red[4];
  int wid = t>>6, ln = t&63;
  if (ln==0) red[wid] = ss;
  __syncthreads();
  float tot = red[0]+red[1]+red[2]+red[3];
  float sc = 1.0f/sqrtf(tot*(1.0f/DM) + EPSF);
  float4 wv = ((const float4*)w)[t];
  float4 ov = { v.x*sc*wv.x, v.y*sc*wv.y, v.z*sc*wv.z, v.w*sc*wv.w };
  ushort4 h, l;
  h.x=f2b(ov.x); l.x=f2b(ov.x - b2f(h.x));
  h.y=f2b(ov.y); l.y=f2b(ov.y - b2f(h.y));
  h.z=f2b(ov.z); l.z=f2b(ov.z - b2f(h.z));
  h.w=f2b(ov.w); l.w=f2b(ov.w - b2f(h.w));
  ((ushort4*)(hi + (size_t)row*DM))[t] = h;
  ((ushort4*)(lo + (size_t)row*DM))[t] = l;
}

// ---------------- split-bf16 MFMA NT GEMM: C = (Ah+Al)@(Bh+Bl)^T (+resid) ------
// 128x128 tile, BK=32, 3 MFMAs per fragment pair (drops Al@Bl, rel err ~2^-18)
__global__ __launch_bounds__(256) void gemm_nt_split(
  const unsigned short* __restrict__ Ah, const unsigned short* __restrict__ Al,
  const unsigned short* __restrict__ Bh0, const unsigned short* __restrict__ Bl0,
  const unsigned short* __restrict__ Bh1, const unsigned short* __restrict__ Bl1,
  const unsigned short* __restrict__ Bh2, const unsigned short* __restrict__ Bl2,
  float* __restrict__ C0, float* __restrict__ C1, float* __restrict__ C2,
  const float* __restrict__ resid, int Kd, int Ncols)
{
  const unsigned short* Bh = (blockIdx.z==0)?Bh0:(blockIdx.z==1)?Bh1:Bh2;
  const unsigned short* Bl = (blockIdx.z==0)?Bl0:(blockIdx.z==1)?Bl1:Bl2;
  float* C = (blockIdx.z==0)?C0:(blockIdx.z==1)?C1:C2;
  __shared__ unsigned short AsH[128*32];
  __shared__ unsigned short AsL[128*32];
  __shared__ unsigned short BsH[128*32];
  __shared__ unsigned short BsL[128*32];
  const int t = threadIdx.x;
  const int w = t>>6, lane = t&63;
  const int wm = w>>1, wn = w&1;
  const int lm = lane&15, fk = (lane>>4)*8;
  const int row0 = blockIdx.y*128, col0 = blockIdx.x*128;
  f32x4_t acc[4][4];
  #pragma unroll
  for (int i=0;i<4;i++)
    #pragma unroll
    for (int j=0;j<4;j++){ f32x4_t z = {0.f,0.f,0.f,0.f}; acc[i][j]=z; }
  for (int k0=0;k0<Kd;k0+=32){
    __syncthreads();
    #pragma unroll
    for (int j=0;j<2;j++){
      const int chunk = j*4 + w;
      const int gt = chunk*64 + lane;
      const int rw_ = gt>>2, kp = (gt&3)*8;
      const size_t aoff = (size_t)(row0+rw_)*Kd + k0 + kp;
      const size_t boff = (size_t)(col0+rw_)*Kd + k0 + kp;
      __builtin_amdgcn_global_load_lds((gas_t)(Ah + aoff), (las_t)(AsH + chunk*512), 16, 0, 0);
      __builtin_amdgcn_global_load_lds((gas_t)(Al + aoff), (las_t)(AsL + chunk*512), 16, 0, 0);
      __builtin_amdgcn_global_load_lds((gas_t)(Bh + boff), (las_t)(BsH + chunk*512), 16, 0, 0);
      __builtin_amdgcn_global_load_lds((gas_t)(Bl + boff), (las_t)(BsL + chunk*512), 16, 0, 0);
    }
    __syncthreads();
    bf16x8_t ah[4], al[4], bh[4], bl[4];
    #pragma unroll
    for (int f=0;f<4;f++){
      const size_t ao = (size_t)(wm*64 + f*16 + lm)*32 + fk;
      const size_t bo = (size_t)(wn*64 + f*16 + lm)*32 + fk;
      ah[f] = *(const bf16x8_t*)(AsH + ao);
      al[f] = *(const bf16x8_t*)(AsL + ao);
      bh[f] = *(const bf16x8_t*)(BsH + bo);
      bl[f] = *(const bf16x8_t*)(BsL + bo);
    }
    #pragma unroll
    for (int i=0;i<4;i++)
      #pragma unroll
      for (int j=0;j<4;j++){
        acc[i][j] = __builtin_amdgcn_mfma_f32_16x16x32_bf16(ah[i], bh[j], acc[i][j], 0, 0, 0);
        acc[i][j] = __builtin_amdgcn_mfma_f32_16x16x32_bf16(al[i], bh[j], acc[i][j], 0, 0, 0);
        acc[i][j] = __builtin_amdgcn_mfma_f32_16x16x32_bf16(ah[i], bl[j], acc[i][j], 0, 0, 0);
      }
  }
  const int rbase = row0 + wm*64 + (lane>>4)*4;
  const int cbase = col0 + wn*64 + lm;
  #pragma unroll
  for (int i=0;i<4;i++)
    #pragma unroll
    for (int j=0;j<4;j++)
      #pragma unroll
      for (int r=0;r<4;r++){
        const size_t idx = (size_t)(rbase + i*16 + r)*Ncols + cbase + j*16;
        float v = acc[i][j][r];
        if (resid) v += resid[idx];
        C[idx] = v;
      }
}

// ---------------- RoPE in-place on qh, kh ----------------
__global__ __launch_bounds__(256) void rope_k(float* __restrict__ qh, float* __restrict__ kh,
  const float* __restrict__ fc, const float* __restrict__ fs){
  int idx = blockIdx.x*256 + threadIdx.x;
  if (idx >= NTOK*NH*32) return;
  int i = idx & 31;
  int h = (idx>>5) & (NH-1);
  int n = idx >> 9;
  int s = n & (SQ-1);
  float c = fc[s*32+i], sn = fs[s*32+i];
  size_t base = (size_t)n*DM + h*HDm + 2*i;
  float xr = qh[base], xi = qh[base+1];
  qh[base]   = xr*c - xi*sn;
  qh[base+1] = xr*sn + xi*c;
  xr = kh[base]; xi = kh[base+1];
  kh[base]   = xr*c - xi*sn;
  kh[base+1] = xr*sn + xi*c;
}

// ---------------- fp32 flash attention, 64x64 tiles ----------------
__global__ __launch_bounds__(256) void flash_k(
  const float* __restrict__ qh, const float* __restrict__ kh, const float* __restrict__ vh,
  float* __restrict__ ctx, const int* __restrict__ causp)
{
  __shared__ float Qt[64][68];   // [hd][qrow]
  __shared__ float KP[64][68];   // Kt [hd][krow] then reused as Pt [krow][qrow]
  __shared__ float Vs[64][68];   // [krow][hd]
  __shared__ float red[64][17];
  __shared__ float mrow[64], lrow[64], arow[64];
  const int qt = blockIdx.x;
  const int b = blockIdx.y >> 4, h = blockIdx.y & 15;
  const int t = threadIdx.x;
  const int row = t>>2, cb = (t&3)*16;
  const int ty = t>>4, tx = t&15;
  const size_t headoff = ((size_t)b*SQ)*DM + (size_t)h*HDm;
  const int q0 = qt*64;
  {
    const float* qp = qh + headoff + (size_t)(q0+row)*DM + cb;
    #pragma unroll
    for (int j=0;j<4;j++){
      float4 v = *(const float4*)(qp + 4*j);
      Qt[cb+4*j+0][row]=v.x; Qt[cb+4*j+1][row]=v.y; Qt[cb+4*j+2][row]=v.z; Qt[cb+4*j+3][row]=v.w;
    }
  }
  if (t<64){ mrow[t]=-1e30f; lrow[t]=0.f; }
  float O[4][4] = {};
  const int causal = *causp;
  const int ktmax = causal ? qt : (SQ/64 - 1);
  for (int kt=0; kt<=ktmax; ++kt){
    const int k0 = kt*64;
    __syncthreads();
    {
      const float* kp_ = kh + headoff + (size_t)(k0+row)*DM + cb;
      const float* vp_ = vh + headoff + (size_t)(k0+row)*DM + cb;
      #pragma unroll
      for (int j=0;j<4;j++){
        float4 v = *(const float4*)(kp_ + 4*j);
        KP[cb+4*j+0][row]=v.x; KP[cb+4*j+1][row]=v.y; KP[cb+4*j+2][row]=v.z; KP[cb+4*j+3][row]=v.w;
        float4 u = *(const float4*)(vp_ + 4*j);
        *(float4*)&Vs[row][cb+4*j] = u;
      }
    }
    __syncthreads();
    float Sv[4][4] = {};
    #pragma unroll 16
    for (int kk=0;kk<64;kk++){
      float4 qa = *(const float4*)&Qt[kk][ty*4];
      float4 kb = *(const float4*)&KP[kk][tx*4];
      float a4[4]={qa.x,qa.y,qa.z,qa.w}, b4[4]={kb.x,kb.y,kb.z,kb.w};
      #pragma unroll
      for (int i=0;i<4;i++)
        #pragma unroll
        for (int j=0;j<4;j++)
          Sv[i][j] = fmaf(a4[i], b4[j], Sv[i][j]);
    }
    #pragma unroll
    for (int i=0;i<4;i++){
      float lm = -3.0e30f;
      #pragma unroll
      for (int j=0;j<4;j++){
        float s = Sv[i][j]*0.125f;
        if (causal && (k0+tx*4+j) > (q0+ty*4+i)) s = -1e30f;
        Sv[i][j] = s;
        lm = fmaxf(lm, s);
      }
      red[ty*4+i][tx] = lm;
    }
    __syncthreads();
    if (t<64){
      float m = red[t][0];
      #pragma unroll
      for (int j=1;j<16;j++) m = fmaxf(m, red[t][j]);
      float mo = mrow[t];
      float mn = fmaxf(mo, m);
      float al = expf(mo - mn);
      mrow[t]=mn; arow[t]=al; lrow[t]*=al;
    }
    __syncthreads();
    #pragma unroll
    for (int i=0;i<4;i++){
      int r = ty*4+i;
      float mn = mrow[r];
      float rs = 0.f;
      #pragma unroll
      for (int j=0;j<4;j++){
        float p = expf(Sv[i][j]-mn);
        KP[tx*4+j][r] = p;   // Pt[key][qrow], aliases Kt (done reading)
        rs += p;
      }
      red[r][tx] = rs;
    }
    __syncthreads();
    if (t<64){
      float s_=0.f;
      #pragma unroll
      for (int j=0;j<16;j++) s_ += red[t][j];
      lrow[t] += s_;
    }
    #pragma unroll
    for (int i=0;i<4;i++){
      float al = arow[ty*4+i];
      #pragma unroll
      for (int j=0;j<4;j++) O[i][j]*=al;
    }
    #pragma unroll 16
    for (int kk=0;kk<64;kk++){
      float4 pa = *(const float4*)&KP[kk][ty*4];
      float4 vb = *(const float4*)&Vs[kk][tx*4];
      float a4[4]={pa.x,pa.y,pa.z,pa.w}, b4[4]={vb.x,vb.y,vb.z,vb.w};
      #pragma unroll
      for (int i=0;i<4;i++)
        #pragma unroll
        for (int j=0;j<4;j++)
          O[i][j] = fmaf(a4[i], b4[j], O[i][j]);
    }
  }
  __syncthreads();
  #pragma unroll
  for (int i=0;i<4;i++){
    float il = 1.0f/lrow[ty*4+i];
    float4 ov = { O[i][0]*il, O[i][1]*il, O[i][2]*il, O[i][3]*il };
    *(float4*)(ctx + headoff + (size_t)(q0+ty*4+i)*DM + tx*4) = ov;
  }
}

// ---------------- router: fp32 logits, top-2, counts ----------------
__global__ __launch_bounds__(256) void router_k(
  const float* __restrict__ hn, const float* __restrict__ rw, const float* __restrict__ rb,
  int* __restrict__ topi, float* __restrict__ topp, int* __restrict__ counts)
{
  const int n = blockIdx.x, t = threadIdx.x;
  float4 x = ((const float4*)(hn + (size_t)n*DM))[t];
  float p[NE];
  #pragma unroll
  for (int e=0;e<NE;e++){
    float4 wv = ((const float4*)(rw + (size_t)e*DM))[t];
    p[e] = x.x*wv.x + x.y*wv.y + x.z*wv.z + x.w*wv.w;
  }
  #pragma unroll
  for (int e=0;e<NE;e++)
    #pragma unroll
    for (int d=32; d; d>>=1) p[e] += __shfl_down(p[e], d, 64);
  __shared__ float red[4][NE];
  int wid=t>>6, ln=t&63;
  if (ln==0){
    #pragma unroll
    for (int e=0;e<NE;e++) red[wid][e]=p[e];
  }
  __syncthreads();
  if (t==0){
    float v1=-3e30f, v2=-3e30f; int i1=0, i2=0;
    for (int e=0;e<NE;e++){
      float v = red[0][e]+red[1][e]+red[2][e]+red[3][e]+rb[e];
      if (v > v1){ v2=v1;i2=i1; v1=v;i1=e; }
      else if (v > v2){ v2=v;i2=e; }
    }
    float ex = expf(v2-v1);
    float g1 = 1.0f/(1.0f+ex);
    float g2 = ex*g1;
    topi[2*n]=i1; topi[2*n+1]=i2;
    topp[2*n]=g1; topp[2*n+1]=g2;
    atomicAdd(&counts[i1],1); atomicAdd(&counts[i2],1);
  }
}

__global__ void offsets_k(const int* __restrict__ counts, int* __restrict__ offs){
  if (blockIdx.x==0 && threadIdx.x==0){
    int run=0;
    for (int e=0;e<NE;e++){ offs[e]=run; run += (counts[e]+127)&~127; }
    offs[NE]=run;
  }
}

__global__ __launch_bounds__(256) void assign_k(const int* __restrict__ topi,
  const int* __restrict__ offs, int* __restrict__ cursor,
  int* __restrict__ list, int* __restrict__ inv){
  int t = blockIdx.x*256 + threadIdx.x;
  if (t >= NTOK*2) return;
  int e = topi[t];
  int slot = atomicAdd(&cursor[e], 1);
  int pos = offs[e] + slot;
  list[pos] = t>>1;
  inv[t] = pos;
}

__global__ __launch_bounds__(256) void gather_k(const float* __restrict__ hn,
  const int* __restrict__ offs, const int* __restrict__ counts, const int* __restrict__ list,
  unsigned short* __restrict__ xg){
  const int p = blockIdx.x;
  if (p >= offs[NE]) return;
  int e=0;
  while (offs[e+1] <= p) ++e;
  const int t = threadIdx.x;
  ushort4 o;
  if (p - offs[e] < counts[e]){
    int n = list[p];
    float4 x = ((const float4*)(hn + (size_t)n*DM))[t];
    o.x=f2b(x.x); o.y=f2b(x.y); o.z=f2b(x.z); o.w=f2b(x.w);
  } else { o.x=0; o.y=0; o.z=0; o.w=0; }
  ((ushort4*)(xg + (size_t)p*DM))[t] = o;
}

// ---------------- bf16 MFMA NT GEMM over expert-compacted rows ----------------
__global__ __launch_bounds__(256) void gemm_moe_bf16(
  const unsigned short* __restrict__ Aall, const unsigned short* __restrict__ Wall,
  unsigned short* __restrict__ Call, const int* __restrict__ offs, int Kd, int Ncols)
{
  const int row0 = blockIdx.y*128;
  if (row0 >= offs[NE]) return;
  int e=0;
  while (offs[e+1] <= row0) ++e;
  const unsigned short* Wp = Wall + (size_t)e*Ncols*Kd;
  const int col0 = blockIdx.x*128;
  __shared__ unsigned short As[128*32];
  __shared__ unsigned short Bs[128*32];
  const int t = threadIdx.x;
  const int w = t>>6, lane = t&63;
  const int wm = w>>1, wn = w&1;
  const int lm = lane&15, fk = (lane>>4)*8;
  f32x4_t acc[4][4];
  #pragma unroll
  for (int i=0;i<4;i++)
    #pragma unroll
    for (int j=0;j<4;j++){ f32x4_t z = {0.f,0.f,0.f,0.f}; acc[i][j]=z; }
  for (int k0=0;k0<Kd;k0+=32){
    __syncthreads();
    #pragma unroll
    for (int j=0;j<2;j++){
      const int chunk = j*4 + w;
      const int gt = chunk*64 + lane;
      const int rw_ = gt>>2, kp = (gt&3)*8;
      __builtin_amdgcn_global_load_lds((gas_t)(Aall + (size_t)(row0+rw_)*Kd + k0 + kp),
                                       (las_t)(As + chunk*512), 16, 0, 0);
      __builtin_amdgcn_global_load_lds((gas_t)(Wp + (size_t)(col0+rw_)*Kd + k0 + kp),
                                       (las_t)(Bs + chunk*512), 16, 0, 0);
    }
    __syncthreads();
    bf16x8_t af[4], bfr[4];
    #pragma unroll
    for (int f=0;f<4;f++){
      af[f]  = *(const bf16x8_t*)(As + (size_t)(wm*64 + f*16 + lm)*32 + fk);
      bfr[f] = *(const bf16x8_t*)(Bs + (size_t)(wn*64 + f*16 + lm)*32 + fk);
    }
    #pragma unroll
    for (int i=0;i<4;i++)
      #pragma unroll
      for (int j=0;j<4;j++)
        acc[i][j] = __builtin_amdgcn_mfma_f32_16x16x32_bf16(af[i], bfr[j], acc[i][j], 0, 0, 0);
  }
  const int rbase = row0 + wm*64 + (lane>>4)*4;
  const int cbase = col0 + wn*64 + lm;
  #pragma unroll
  for (int i=0;i<4;i++)
    #pragma unroll
    for (int j=0;j<4;j++)
      #pragma unroll
      for (int r=0;r<4;r++)
        Call[(size_t)(rbase + i*16 + r)*Ncols + cbase + j*16] = f2b(acc[i][j][r]);
}

__global__ __launch_bounds__(256) void silu_mul_k(unsigned short* __restrict__ h1,
                                                  const unsigned short* __restrict__ h3){
  size_t i = (size_t)blockIdx.x*256 + threadIdx.x;
  ushort4 a = ((const ushort4*)h1)[i];
  ushort4 b = ((const ushort4*)h3)[i];
  ushort4 o;
  float fa, fb, s_;
  fa=b2f(a.x); fb=b2f(b.x); s_=fa/(1.f+__expf(-fa)); o.x=f2b(s_*fb);
  fa=b2f(a.y); fb=b2f(b.y); s_=fa/(1.f+__expf(-fa)); o.y=f2b(s_*fb);
  fa=b2f(a.z); fb=b2f(b.z); s_=fa/(1.f+__expf(-fa)); o.z=f2b(s_*fb);
  fa=b2f(a.w); fb=b2f(b.w); s_=fa/(1.f+__expf(-fa)); o.w=f2b(s_*fb);
  ((ushort4*)h1)[i] = o;
}

__global__ __launch_bounds__(256) void combine_k(const float* __restrict__ h,
  const unsigned short* __restrict__ yb, const float* __restrict__ topp,
  const int* __restrict__ inv, float* __restrict__ out)
{
  const int n = blockIdx.x, t = threadIdx.x;
  const int p0 = inv[2*n], p1 = inv[2*n+1];
  const float g0 = topp[2*n], g1 = topp[2*n+1];
  float4 hv = ((const float4*)(h + (size_t)n*DM))[t];
  ushort4 y0 = ((const ushort4*)(yb + (size_t)p0*DM))[t];
  ushort4 y1 = ((const ushort4*)(yb + (size_t)p1*DM))[t];
  float4 ov;
  ov.x = hv.x + g0*b2f(y0.x) + g1*b2f(y1.x);
  ov.y = hv.y + g0*b2f(y0.y) + g1*b2f(y1.y);
  ov.z = hv.z + g0*b2f(y0.z) + g1*b2f(y1.z);
  ov.w = hv.w + g0*b2f(y0.w) + g1*b2f(y1.w);
  ((float4*)(out + (size_t)n*DM))[t] = ov;
}

extern "C" void kernel_launch(void* const* d_in, const int* in_sizes, int n_in,
                              void* d_out, int out_size, void* d_ws, size_t ws_size,
                              hipStream_t stream)
{
  (void)in_sizes; (void)n_in; (void)out_size; (void)ws_size;
  const float* q    = (const float*)d_in[0];
  const float* fc   = (const float*)d_in[3];
  const float* fs   = (const float*)d_in[4];
  const float* attw = (const float*)d_in[5];
  const float* ffnw = (const float*)d_in[6];
  const float* wq   = (const float*)d_in[7];
  const float* wk   = (const float*)d_in[8];
  const float* wv   = (const float*)d_in[9];
  const float* wo   = (const float*)d_in[10];
  const float* rw   = (const float*)d_in[11];
  const float* rb   = (const float*)d_in[12];
  const float* w1   = (const float*)d_in[13];
  const float* w2   = (const float*)d_in[14];
  const float* w3   = (const float*)d_in[15];
  const int*   caus = (const int*)d_in[16];
  float* out = (float*)d_out;

  char* ws = (char*)d_ws;
  size_t off = 0;
  auto take = [&](size_t bytes)->char*{ char* r = ws + off; off += (bytes + 255) & ~(size_t)255; return r; };
  unsigned short* qnh = (unsigned short*)take((size_t)NTOK*DM*2);
  unsigned short* qnl = (unsigned short*)take((size_t)NTOK*DM*2);
  float* qh   = (float*)take((size_t)NTOK*DM*4);
  float* kh   = (float*)take((size_t)NTOK*DM*4);
  float* vh   = (float*)take((size_t)NTOK*DM*4);
  float* hbuf = (float*)take((size_t)NTOK*DM*4);
  unsigned short* h1  = (unsigned short*)take((size_t)RTOT*FFd*2);
  unsigned short* h3  = (unsigned short*)take((size_t)RTOT*FFd*2);
  unsigned short* yb  = (unsigned short*)take((size_t)RTOT*DM*2);
  unsigned short* w1b = (unsigned short*)take((size_t)NE*FFd*DM*2);
  unsigned short* w3b = (unsigned short*)take((size_t)NE*FFd*DM*2);
  unsigned short* w2b = (unsigned short*)take((size_t)NE*FFd*DM*2);
  int*   counts = (int*)take(64);
  int*   cursor = counts + 8;
  int*   offs   = (int*)take(64);
  int*   topi   = (int*)take((size_t)NTOK*2*4);
  float* topp   = (float*)take((size_t)NTOK*2*4);
  int*   list   = (int*)take((size_t)RTOT*4);
  int*   inv    = (int*)take((size_t)NTOK*2*4);

  // aliases (lifetimes disjoint):
  float* ctx = (float*)qnh;                       // flash output overwrites qn splits (16.8MB = qnh+qnl)
  unsigned short* ctxh = (unsigned short*)qh;     // ctx splits overwrite qh after flash
  unsigned short* ctxl = ctxh + (size_t)NTOK*DM;
  float* hn = kh;                                 // rmsnorm2 output overwrites kh after flash
  unsigned short* xg = yb;                        // gathered tokens; dead before yb written
  unsigned short* wqh = (unsigned short*)h1;      // attn weight splits live in h1 region (dead before MoE)
  unsigned short* wql = wqh + (size_t)DM*DM;
  unsigned short* wkh = wql + (size_t)DM*DM;
  unsigned short* wkl = wkh + (size_t)DM*DM;
  unsigned short* wvh = wkl + (size_t)DM*DM;
  unsigned short* wvl = wvh + (size_t)DM*DM;
  unsigned short* woh = wvl + (size_t)DM*DM;
  unsigned short* wol = woh + (size_t)DM*DM;

  const int nw4 = NE*FFd*DM/4;  // 8388608
  convert_k<<<nw4/256, 256, 0, stream>>>(w1, w1b, nw4);
  convert_k<<<nw4/256, 256, 0, stream>>>(w3, w3b, nw4);
  convert_k<<<nw4/256, 256, 0, stream>>>(w2, w2b, nw4);

  const int nwq4 = DM*DM/4;  // 262144
  split_k<<<nwq4/256, 256, 0, stream>>>(wq, wqh, wql, nwq4);
  split_k<<<nwq4/256, 256, 0, stream>>>(wk, wkh, wkl, nwq4);
  split_k<<<nwq4/256, 256, 0, stream>>>(wv, wvh, wvl, nwq4);
  split_k<<<nwq4/256, 256, 0, stream>>>(wo, woh, wol, nwq4);

  rmsnorm_split_k<<<NTOK, 256, 0, stream>>>(q, attw, qnh, qnl);
  gemm_nt_split<<<dim3(8,32,3), 256, 0, stream>>>(qnh, qnl,
      wqh, wql, wkh, wkl, wvh, wvl, qh, kh, vh, nullptr, DM, DM);
  rope_k<<<NTOK*NH*32/256, 256, 0, stream>>>(qh, kh, fc, fs);
  flash_k<<<dim3(SQ/64, NB*NH), 256, 0, stream>>>(qh, kh, vh, ctx, caus);
  split_k<<<NTOK*DM/4/256, 256, 0, stream>>>(ctx, ctxh, ctxl, NTOK*DM/4);
  gemm_nt_split<<<dim3(8,32,1), 256, 0, stream>>>(ctxh, ctxl,
      woh, wol, woh, wol, woh, wol, hbuf, hbuf, hbuf, q, DM, DM);
  rmsnorm_k<<<NTOK, 256, 0, stream>>>(hbuf, ffnw, hn);

  hipMemsetAsync(counts, 0, 64, stream);
  router_k<<<NTOK, 256, 0, stream>>>(hn, rw, rb, topi, topp, counts);
  offsets_k<<<1, 64, 0, stream>>>(counts, offs);
  assign_k<<<NTOK*2/256, 256, 0, stream>>>(topi, offs, cursor, list, inv);
  gather_k<<<RTOT, 256, 0, stream>>>(hn, offs, counts, list, xg);

  gemm_moe_bf16<<<dim3(FFd/128, RTOT/128), 256, 0, stream>>>(xg, w1b, h1, offs, DM, FFd);
  gemm_moe_bf16<<<dim3(FFd/128, RTOT/128), 256, 0, stream>>>(xg, w3b, h3, offs, DM, FFd);
  silu_mul_k<<<RTOT*FFd/4/256, 256, 0, stream>>>(h1, h3);
  gemm_moe_bf16<<<dim3(DM/128, RTOT/128), 256, 0, stream>>>(h1, w2b, yb, offs, FFd, DM);
  combine_k<<<NTOK, 256, 0, stream>>>(hbuf, yb, topp, inv, out);
}